// Round 2
// baseline (306.566 us; speedup 1.0000x reference)
//
#include <hip/hip_runtime.h>

// CenterLoss via closed-form decomposition (clamp is provably inactive for
// these inputs: pairwise sq-dists concentrate at 2D=4096 +- ~130; min over
// 8.2M pairs ~3400 >> 1e-12, max ~4800 << 1e12):
//   Sum_all  = C*Sx + B*Sc - 2*(sum_x . sum_c)
//   Sum_diag = Sx + Scl - 2*Sdot
//   loss = Sum_diag/B - 0.001*(Sum_all - Sum_diag)/(B*(C-1))
// where Sx = sum ||x_b||^2, Sc = sum ||c_c||^2, Scl = sum_b ||c_{l_b}||^2,
// Sdot = sum_b x_b . c_{l_b}, and sum_x.sum_c computed as sum_b (x_b . sc)
// with sc = column-sum of centers (pass 1). Stream serializes pass1->pass2,
// so the sc dependency costs nothing.

#define DD 2048
#define NB 8192
#define NC 1000
#define D4 (DD / 4)   // 512 float4 per row
#define THREADS 256

// workspace: double scalars[8] at offset 0; float sc[DD] at offset 64
#define WS_BYTES (64 + DD * 4)

__device__ __forceinline__ float dot4(float4 a, float4 b) {
    return a.x * b.x + a.y * b.y + a.z * b.z + a.w * b.w;
}

// Pass 1: centers -> Sc (fp64 atomic) + sc[D] column sums (fp32 atomics).
// 125 blocks x 8 rows = 1000 rows exactly.
__global__ __launch_bounds__(THREADS) void centers_kernel(
        const float4* __restrict__ c4, double* __restrict__ scalars,
        float* __restrict__ sc) {
    const int ROWS = 8;
    int row0 = blockIdx.x * ROWS;
    int t = threadIdx.x;

    float4 cs0 = make_float4(0.f, 0.f, 0.f, 0.f);
    float4 cs1 = make_float4(0.f, 0.f, 0.f, 0.f);
    float csq = 0.f;

#pragma unroll
    for (int r = 0; r < ROWS; ++r) {
        const float4* cr = c4 + (size_t)(row0 + r) * D4;
        float4 a = cr[t];
        float4 b = cr[256 + t];
        cs0.x += a.x; cs0.y += a.y; cs0.z += a.z; cs0.w += a.w;
        cs1.x += b.x; cs1.y += b.y; cs1.z += b.z; cs1.w += b.w;
        csq += dot4(a, a) + dot4(b, b);
    }

    atomicAdd(&sc[4 * t + 0], cs0.x);
    atomicAdd(&sc[4 * t + 1], cs0.y);
    atomicAdd(&sc[4 * t + 2], cs0.z);
    atomicAdd(&sc[4 * t + 3], cs0.w);
    atomicAdd(&sc[1024 + 4 * t + 0], cs1.x);
    atomicAdd(&sc[1024 + 4 * t + 1], cs1.y);
    atomicAdd(&sc[1024 + 4 * t + 2], cs1.z);
    atomicAdd(&sc[1024 + 4 * t + 3], cs1.w);

    __shared__ float red[THREADS / 64];
    for (int off = 32; off > 0; off >>= 1) csq += __shfl_down(csq, off, 64);
    int lane = t & 63, wv = t >> 6;
    if (lane == 0) red[wv] = csq;
    __syncthreads();
    if (t == 0) {
        double s = 0.0;
        for (int w = 0; w < THREADS / 64; ++w) s += (double)red[w];
        atomicAdd(&scalars[0], s);
    }
}

// Pass 2: x -> Sx, Sdot, Scl, S2. 2048 blocks x 4 rows.
// Labels hoisted as one int4 broadcast; all 16 float4 loads issued
// independently so the memory system pipelines them.
__global__ __launch_bounds__(THREADS, 4) void x_kernel(
        const float4* __restrict__ x4, const float4* __restrict__ c4,
        const int* __restrict__ labels, const float4* __restrict__ sc4,
        double* __restrict__ scalars) {
    int b = blockIdx.x;
    int t = threadIdx.x;

    float4 scv0 = sc4[t];
    float4 scv1 = sc4[256 + t];

    int4 lab = ((const int4*)labels)[b];   // rows 4b..4b+3, broadcast

    const float4* xr = x4 + (size_t)(4 * b) * D4 + t;
    float4 xa0 = xr[0 * D4], xb0 = xr[0 * D4 + 256];
    float4 xa1 = xr[1 * D4], xb1 = xr[1 * D4 + 256];
    float4 xa2 = xr[2 * D4], xb2 = xr[2 * D4 + 256];
    float4 xa3 = xr[3 * D4], xb3 = xr[3 * D4 + 256];

    const float4* c0 = c4 + (size_t)lab.x * D4 + t;
    const float4* c1 = c4 + (size_t)lab.y * D4 + t;
    const float4* c2 = c4 + (size_t)lab.z * D4 + t;
    const float4* c3 = c4 + (size_t)lab.w * D4 + t;
    float4 ca0 = c0[0], cb0 = c0[256];
    float4 ca1 = c1[0], cb1 = c1[256];
    float4 ca2 = c2[0], cb2 = c2[256];
    float4 ca3 = c3[0], cb3 = c3[256];

    float sx = dot4(xa0, xa0) + dot4(xb0, xb0)
             + dot4(xa1, xa1) + dot4(xb1, xb1)
             + dot4(xa2, xa2) + dot4(xb2, xb2)
             + dot4(xa3, xa3) + dot4(xb3, xb3);
    float sdot = dot4(xa0, ca0) + dot4(xb0, cb0)
               + dot4(xa1, ca1) + dot4(xb1, cb1)
               + dot4(xa2, ca2) + dot4(xb2, cb2)
               + dot4(xa3, ca3) + dot4(xb3, cb3);
    float scl = dot4(ca0, ca0) + dot4(cb0, cb0)
              + dot4(ca1, ca1) + dot4(cb1, cb1)
              + dot4(ca2, ca2) + dot4(cb2, cb2)
              + dot4(ca3, ca3) + dot4(cb3, cb3);
    float s2 = dot4(xa0, scv0) + dot4(xb0, scv1)
             + dot4(xa1, scv0) + dot4(xb1, scv1)
             + dot4(xa2, scv0) + dot4(xb2, scv1)
             + dot4(xa3, scv0) + dot4(xb3, scv1);

    __shared__ float red[4][THREADS / 64];
    for (int off = 32; off > 0; off >>= 1) {
        sx   += __shfl_down(sx, off, 64);
        sdot += __shfl_down(sdot, off, 64);
        scl  += __shfl_down(scl, off, 64);
        s2   += __shfl_down(s2, off, 64);
    }
    int lane = t & 63, wv = t >> 6;
    if (lane == 0) {
        red[0][wv] = sx; red[1][wv] = sdot; red[2][wv] = scl; red[3][wv] = s2;
    }
    __syncthreads();
    if (t == 0) {
        double a = 0.0, bb = 0.0, c = 0.0, d = 0.0;
        for (int w = 0; w < THREADS / 64; ++w) {
            a  += (double)red[0][w];
            bb += (double)red[1][w];
            c  += (double)red[2][w];
            d  += (double)red[3][w];
        }
        atomicAdd(&scalars[1], a);
        atomicAdd(&scalars[2], bb);
        atomicAdd(&scalars[3], c);
        atomicAdd(&scalars[4], d);
    }
}

__global__ void finalize_kernel(const double* __restrict__ scalars,
                                float* __restrict__ out) {
    if (threadIdx.x == 0 && blockIdx.x == 0) {
        double Sc = scalars[0], Sx = scalars[1], Sdot = scalars[2];
        double Scl = scalars[3], S2 = scalars[4];
        double sum_all  = (double)NC * Sx + (double)NB * Sc - 2.0 * S2;
        double sum_diag = Sx + Scl - 2.0 * Sdot;
        double center_loss = sum_diag / (double)NB;
        double sep_loss = (sum_all - sum_diag) / ((double)NB * (double)(NC - 1));
        out[0] = (float)(center_loss - 0.001 * sep_loss);
    }
}

extern "C" void kernel_launch(void* const* d_in, const int* in_sizes, int n_in,
                              void* d_out, int out_size, void* d_ws, size_t ws_size,
                              hipStream_t stream) {
    const float4* x4 = (const float4*)d_in[0];       // [8192, 2048] f32
    const float4* c4 = (const float4*)d_in[1];       // [1000, 2048] f32
    const int* labels = (const int*)d_in[2];         // [8192] i32

    double* scalars = (double*)d_ws;
    float* sc = (float*)((char*)d_ws + 64);
    float* out = (float*)d_out;

    hipMemsetAsync(d_ws, 0, WS_BYTES, stream);

    centers_kernel<<<NC / 8, THREADS, 0, stream>>>(c4, scalars, sc);   // 125
    x_kernel<<<NB / 4, THREADS, 0, stream>>>(x4, c4, labels,           // 2048
                                             (const float4*)sc, scalars);
    finalize_kernel<<<1, 64, 0, stream>>>(scalars, out);
}

// Round 3
// 198.663 us; speedup vs baseline: 1.5431x; 1.5431x over previous
//
#include <hip/hip_runtime.h>

// CenterLoss, closed form (clamp provably inactive: pairwise sq-dists are
// 4096 +- ~130 for these inputs, far inside [1e-12, 1e12]):
//   Sum_all  = C*Sx + B*Sc - 2*(gx . sc)          gx = colsum(x), sc = colsum(centers)
//   Sum_diag = Sx + Scl - 2*Sdot
//   loss = Sum_diag/B - 0.001*(Sum_all - Sum_diag)/(B*(C-1))
// Single fused kernel: x-blocks compute {Sx, Sdot, Scl} partials + gx atomics;
// center-blocks compute {Sc} partials + sc atomics. No cross-dependency, so
// both run concurrently. Per-block partials go to private slots (no scalar
// atomics); a 1-block finalize reduces slots and computes gx.sc.

#define DD 2048
#define NB 8192
#define NC 1000
#define D4 (DD / 4)          // 512 float4 per row
#define THREADS 256
#define XROWS 8
#define CROWS 4
#define XBLOCKS (NB / XROWS) // 1024
#define CBLOCKS (NC / CROWS) // 250
#define NBLOCKS (XBLOCKS + CBLOCKS)

// ws layout: float gx[2048] @ 0 ; float sc[2048] @ 8192 ;
//            float4 partials[NBLOCKS] @ 16384  (x: {sx,sdot,scl,0}, c: {0,0,0,csq})
#define GX_OFF 0
#define SC_OFF 8192
#define PART_OFF 16384
#define ZERO_BYTES 16384     // only gx/sc need zeroing (atomic targets)

__device__ __forceinline__ float dot4(float4 a, float4 b) {
    return a.x * b.x + a.y * b.y + a.z * b.z + a.w * b.w;
}

__global__ __launch_bounds__(THREADS) void main_kernel(
        const float4* __restrict__ x4, const float4* __restrict__ c4,
        const int* __restrict__ labels, float* __restrict__ gx,
        float* __restrict__ sc, float4* __restrict__ partials) {
    const int t = threadIdx.x;
    const int b = blockIdx.x;
    float4 out = make_float4(0.f, 0.f, 0.f, 0.f);  // {sx, sdot, scl, csq}

    if (b < XBLOCKS) {
        const int rows0 = b * XROWS;
        int labs[XROWS];
#pragma unroll
        for (int r = 0; r < XROWS; ++r) labs[r] = labels[rows0 + r];  // uniform

        const float4* xp = x4 + (size_t)rows0 * D4 + t;
        float4 cs0 = make_float4(0.f, 0.f, 0.f, 0.f);
        float4 cs1 = make_float4(0.f, 0.f, 0.f, 0.f);
        float sx = 0.f, sdot = 0.f, scl = 0.f;

        // software pipeline: row r+1's 4 loads issue before row r is consumed
        float4 xa = xp[0], xb = xp[256];
        const float4* cp = c4 + (size_t)labs[0] * D4 + t;
        float4 ca = cp[0], cb = cp[256];
#pragma unroll
        for (int r = 0; r < XROWS; ++r) {
            float4 nxa, nxb, nca, ncb;
            if (r + 1 < XROWS) {
                nxa = xp[(r + 1) * D4];
                nxb = xp[(r + 1) * D4 + 256];
                const float4* np = c4 + (size_t)labs[r + 1] * D4 + t;
                nca = np[0];
                ncb = np[256];
            }
            sx   += dot4(xa, xa) + dot4(xb, xb);
            sdot += dot4(xa, ca) + dot4(xb, cb);
            scl  += dot4(ca, ca) + dot4(cb, cb);
            cs0.x += xa.x; cs0.y += xa.y; cs0.z += xa.z; cs0.w += xa.w;
            cs1.x += xb.x; cs1.y += xb.y; cs1.z += xb.z; cs1.w += xb.w;
            if (r + 1 < XROWS) { xa = nxa; xb = nxb; ca = nca; cb = ncb; }
        }

        atomicAdd(&gx[4 * t + 0], cs0.x);
        atomicAdd(&gx[4 * t + 1], cs0.y);
        atomicAdd(&gx[4 * t + 2], cs0.z);
        atomicAdd(&gx[4 * t + 3], cs0.w);
        atomicAdd(&gx[1024 + 4 * t + 0], cs1.x);
        atomicAdd(&gx[1024 + 4 * t + 1], cs1.y);
        atomicAdd(&gx[1024 + 4 * t + 2], cs1.z);
        atomicAdd(&gx[1024 + 4 * t + 3], cs1.w);
        out.x = sx; out.y = sdot; out.z = scl;
    } else {
        const int rows0 = (b - XBLOCKS) * CROWS;
        const float4* cp = c4 + (size_t)rows0 * D4 + t;
        float4 cs0 = make_float4(0.f, 0.f, 0.f, 0.f);
        float4 cs1 = make_float4(0.f, 0.f, 0.f, 0.f);
        float csq = 0.f;
#pragma unroll
        for (int r = 0; r < CROWS; ++r) {
            float4 a = cp[r * D4];
            float4 bb = cp[r * D4 + 256];
            cs0.x += a.x; cs0.y += a.y; cs0.z += a.z; cs0.w += a.w;
            cs1.x += bb.x; cs1.y += bb.y; cs1.z += bb.z; cs1.w += bb.w;
            csq += dot4(a, a) + dot4(bb, bb);
        }
        atomicAdd(&sc[4 * t + 0], cs0.x);
        atomicAdd(&sc[4 * t + 1], cs0.y);
        atomicAdd(&sc[4 * t + 2], cs0.z);
        atomicAdd(&sc[4 * t + 3], cs0.w);
        atomicAdd(&sc[1024 + 4 * t + 0], cs1.x);
        atomicAdd(&sc[1024 + 4 * t + 1], cs1.y);
        atomicAdd(&sc[1024 + 4 * t + 2], cs1.z);
        atomicAdd(&sc[1024 + 4 * t + 3], cs1.w);
        out.w = csq;
    }

    // block-reduce the 4 partials, thread 0 writes the private slot
    __shared__ float red[4][THREADS / 64];
    for (int off = 32; off > 0; off >>= 1) {
        out.x += __shfl_down(out.x, off, 64);
        out.y += __shfl_down(out.y, off, 64);
        out.z += __shfl_down(out.z, off, 64);
        out.w += __shfl_down(out.w, off, 64);
    }
    const int lane = t & 63, wv = t >> 6;
    if (lane == 0) {
        red[0][wv] = out.x; red[1][wv] = out.y;
        red[2][wv] = out.z; red[3][wv] = out.w;
    }
    __syncthreads();
    if (t == 0) {
        float4 s;
        s.x = red[0][0] + red[0][1] + red[0][2] + red[0][3];
        s.y = red[1][0] + red[1][1] + red[1][2] + red[1][3];
        s.z = red[2][0] + red[2][1] + red[2][2] + red[2][3];
        s.w = red[3][0] + red[3][1] + red[3][2] + red[3][3];
        partials[b] = s;
    }
}

__global__ __launch_bounds__(THREADS) void finalize_kernel(
        const float4* __restrict__ gx4, const float4* __restrict__ sc4,
        const float4* __restrict__ partials, float* __restrict__ out) {
    const int t = threadIdx.x;

    double s2 = (double)dot4(gx4[t], sc4[t]) +
                (double)dot4(gx4[256 + t], sc4[256 + t]);
    double sx = 0.0, sdot = 0.0, scl = 0.0, csq = 0.0;
    for (int i = t; i < NBLOCKS; i += THREADS) {
        float4 p = partials[i];
        sx += (double)p.x; sdot += (double)p.y;
        scl += (double)p.z; csq += (double)p.w;
    }

    __shared__ double red[5][THREADS / 64];
    for (int off = 32; off > 0; off >>= 1) {
        s2   += __shfl_down(s2, off, 64);
        sx   += __shfl_down(sx, off, 64);
        sdot += __shfl_down(sdot, off, 64);
        scl  += __shfl_down(scl, off, 64);
        csq  += __shfl_down(csq, off, 64);
    }
    const int lane = t & 63, wv = t >> 6;
    if (lane == 0) {
        red[0][wv] = s2; red[1][wv] = sx; red[2][wv] = sdot;
        red[3][wv] = scl; red[4][wv] = csq;
    }
    __syncthreads();
    if (t == 0) {
        double S2 = red[0][0] + red[0][1] + red[0][2] + red[0][3];
        double Sx = red[1][0] + red[1][1] + red[1][2] + red[1][3];
        double Sdot = red[2][0] + red[2][1] + red[2][2] + red[2][3];
        double Scl = red[3][0] + red[3][1] + red[3][2] + red[3][3];
        double Sc = red[4][0] + red[4][1] + red[4][2] + red[4][3];
        double sum_all = (double)NC * Sx + (double)NB * Sc - 2.0 * S2;
        double sum_diag = Sx + Scl - 2.0 * Sdot;
        double center_loss = sum_diag / (double)NB;
        double sep_loss =
            (sum_all - sum_diag) / ((double)NB * (double)(NC - 1));
        out[0] = (float)(center_loss - 0.001 * sep_loss);
    }
}

extern "C" void kernel_launch(void* const* d_in, const int* in_sizes, int n_in,
                              void* d_out, int out_size, void* d_ws, size_t ws_size,
                              hipStream_t stream) {
    const float4* x4 = (const float4*)d_in[0];   // [8192, 2048] f32
    const float4* c4 = (const float4*)d_in[1];   // [1000, 2048] f32
    const int* labels = (const int*)d_in[2];     // [8192] i32

    float* gx = (float*)((char*)d_ws + GX_OFF);
    float* sc = (float*)((char*)d_ws + SC_OFF);
    float4* partials = (float4*)((char*)d_ws + PART_OFF);
    float* out = (float*)d_out;

    hipMemsetAsync(d_ws, 0, ZERO_BYTES, stream);

    main_kernel<<<NBLOCKS, THREADS, 0, stream>>>(x4, c4, labels, gx, sc,
                                                 partials);
    finalize_kernel<<<1, THREADS, 0, stream>>>((const float4*)gx,
                                               (const float4*)sc, partials, out);
}

// Round 4
// 154.492 us; speedup vs baseline: 1.9844x; 1.2859x over previous
//
#include <hip/hip_runtime.h>

// CenterLoss, closed form (clamp provably inactive: pairwise sq-dists are
// 4096 +- ~130 for these inputs, far inside [1e-12, 1e12]; verified absmax=0
// in rounds 1-3):
//   Sum_all  = C*Sx + B*Sc - 2*(gx . sc)     gx = colsum(x), sc = colsum(centers)
//   Sum_diag = Sx + Scl - 2*Sdot
//   loss = Sum_diag/B - 0.001*(Sum_all - Sum_diag)/(B*(C-1))
//
// ZERO atomics (round-3 post-mortem: 2.6M device-scope fp32 atomics wrote
// through to the coherence point, 40.8 MB HBM writes, kernel 2x slower).
// Every block writes private slots; reduce_kernel folds column-sum partials
// and computes S2 partials; finalize_kernel combines in fp64.
// No memset needed: all consumed ws bytes are written every call.

#define DD 2048
#define NB 8192
#define NC 1000
#define D4 (DD / 4)          // 512 float4 per row
#define THREADS 256
#define XROWS 8
#define CROWS 4
#define XBLOCKS (NB / XROWS) // 1024
#define CBLOCKS (NC / CROWS) // 250
#define NBLOCKS (XBLOCKS + CBLOCKS)
#define RBLOCKS 64           // reduce kernel blocks (32 cols each)

// ws layout (bytes):
//   xp  [XBLOCKS][2048] f32 @ 0          (8 MB)   per-x-block column sums
//   cp  [CBLOCKS][2048] f32 @ 8388608    (2 MB)   per-c-block column sums
//   part[NBLOCKS] float4    @ 10436608   (20 KB)  {sx, sdot, scl, csq}
//   s2p [RBLOCKS] f32       @ 10456992   (256 B)  partials of gx.sc
#define XP_OFF   0
#define CP_OFF   8388608
#define PART_OFF 10436608
#define S2_OFF   10456992

__device__ __forceinline__ float dot4(float4 a, float4 b) {
    return a.x * b.x + a.y * b.y + a.z * b.z + a.w * b.w;
}

__global__ __launch_bounds__(THREADS) void main_kernel(
        const float4* __restrict__ x4, const float4* __restrict__ c4,
        const int* __restrict__ labels, float4* __restrict__ xp,
        float4* __restrict__ cp, float4* __restrict__ partials) {
    const int t = threadIdx.x;
    const int b = blockIdx.x;
    float4 out = make_float4(0.f, 0.f, 0.f, 0.f);  // {sx, sdot, scl, csq}

    if (b < XBLOCKS) {
        const int rows0 = b * XROWS;
        int labs[XROWS];
#pragma unroll
        for (int r = 0; r < XROWS; ++r) labs[r] = labels[rows0 + r];  // uniform

        const float4* xr = x4 + (size_t)rows0 * D4 + t;
        float4 cs0 = make_float4(0.f, 0.f, 0.f, 0.f);
        float4 cs1 = make_float4(0.f, 0.f, 0.f, 0.f);
        float sx = 0.f, sdot = 0.f, scl = 0.f;

        // depth-1 software pipeline (round-3 shape, VGPR~60): next row's 4
        // loads are in flight while current row is consumed.
        float4 xa = xr[0], xb = xr[256];
        const float4* cr = c4 + (size_t)labs[0] * D4 + t;
        float4 ca = cr[0], cb = cr[256];
#pragma unroll
        for (int r = 0; r < XROWS; ++r) {
            float4 nxa, nxb, nca, ncb;
            if (r + 1 < XROWS) {
                nxa = xr[(r + 1) * D4];
                nxb = xr[(r + 1) * D4 + 256];
                const float4* np = c4 + (size_t)labs[r + 1] * D4 + t;
                nca = np[0];
                ncb = np[256];
            }
            sx   += dot4(xa, xa) + dot4(xb, xb);
            sdot += dot4(xa, ca) + dot4(xb, cb);
            scl  += dot4(ca, ca) + dot4(cb, cb);
            cs0.x += xa.x; cs0.y += xa.y; cs0.z += xa.z; cs0.w += xa.w;
            cs1.x += xb.x; cs1.y += xb.y; cs1.z += xb.z; cs1.w += xb.w;
            if (r + 1 < XROWS) { xa = nxa; xb = nxb; ca = nca; cb = ncb; }
        }

        // private slot, coalesced float4 stores (thread t owns cols 4t..4t+3
        // and 1024+4t..1024+4t+3)
        xp[(size_t)b * 512 + t] = cs0;
        xp[(size_t)b * 512 + 256 + t] = cs1;
        out.x = sx; out.y = sdot; out.z = scl;
    } else {
        const int cb = b - XBLOCKS;
        const int rows0 = cb * CROWS;
        const float4* cr = c4 + (size_t)rows0 * D4 + t;
        float4 cs0 = make_float4(0.f, 0.f, 0.f, 0.f);
        float4 cs1 = make_float4(0.f, 0.f, 0.f, 0.f);
        float csq = 0.f;
#pragma unroll
        for (int r = 0; r < CROWS; ++r) {
            float4 a = cr[r * D4];
            float4 bb = cr[r * D4 + 256];
            cs0.x += a.x; cs0.y += a.y; cs0.z += a.z; cs0.w += a.w;
            cs1.x += bb.x; cs1.y += bb.y; cs1.z += bb.z; cs1.w += bb.w;
            csq += dot4(a, a) + dot4(bb, bb);
        }
        cp[(size_t)cb * 512 + t] = cs0;
        cp[(size_t)cb * 512 + 256 + t] = cs1;
        out.w = csq;
    }

    __shared__ float red[4][THREADS / 64];
    for (int off = 32; off > 0; off >>= 1) {
        out.x += __shfl_down(out.x, off, 64);
        out.y += __shfl_down(out.y, off, 64);
        out.z += __shfl_down(out.z, off, 64);
        out.w += __shfl_down(out.w, off, 64);
    }
    const int lane = t & 63, wv = t >> 6;
    if (lane == 0) {
        red[0][wv] = out.x; red[1][wv] = out.y;
        red[2][wv] = out.z; red[3][wv] = out.w;
    }
    __syncthreads();
    if (t == 0) {
        float4 s;
        s.x = red[0][0] + red[0][1] + red[0][2] + red[0][3];
        s.y = red[1][0] + red[1][1] + red[1][2] + red[1][3];
        s.z = red[2][0] + red[2][1] + red[2][2] + red[2][3];
        s.w = red[3][0] + red[3][1] + red[3][2] + red[3][3];
        partials[b] = s;
    }
}

// 64 blocks x 32 columns: fold xp (1024 rows) and cp (250 rows) into column
// sums, then the per-block partial of S2 = gx.sc. Thread map: bsub = t>>5
// (8-way row split), cloc = t&31.
__global__ __launch_bounds__(THREADS) void reduce_kernel(
        const float* __restrict__ xp, const float* __restrict__ cp,
        float* __restrict__ s2p) {
    const int t = threadIdx.x;
    const int bsub = t >> 5;           // 0..7
    const int cloc = t & 31;           // 0..31
    const int col = blockIdx.x * 32 + cloc;

    float gx = 0.f, sc = 0.f;
    for (int b = bsub; b < XBLOCKS; b += 8) gx += xp[(size_t)b * DD + col];
    for (int b = bsub; b < CBLOCKS; b += 8) sc += cp[(size_t)b * DD + col];

    __shared__ float gxs[8][32], scs[8][32];
    gxs[bsub][cloc] = gx;
    scs[bsub][cloc] = sc;
    __syncthreads();
    if (t < 32) {
        float g = 0.f, s = 0.f;
#pragma unroll
        for (int w = 0; w < 8; ++w) { g += gxs[w][t]; s += scs[w][t]; }
        float prod = g * s;
        for (int off = 16; off > 0; off >>= 1)
            prod += __shfl_down(prod, off, 64);
        if (t == 0) s2p[blockIdx.x] = prod;
    }
}

__global__ __launch_bounds__(THREADS) void finalize_kernel(
        const float4* __restrict__ partials, const float* __restrict__ s2p,
        float* __restrict__ out) {
    const int t = threadIdx.x;

    double sx = 0.0, sdot = 0.0, scl = 0.0, csq = 0.0, s2 = 0.0;
    for (int i = t; i < NBLOCKS; i += THREADS) {
        float4 p = partials[i];
        sx += (double)p.x; sdot += (double)p.y;
        scl += (double)p.z; csq += (double)p.w;
    }
    if (t < RBLOCKS) s2 = (double)s2p[t];

    __shared__ double red[5][THREADS / 64];
    for (int off = 32; off > 0; off >>= 1) {
        sx   += __shfl_down(sx, off, 64);
        sdot += __shfl_down(sdot, off, 64);
        scl  += __shfl_down(scl, off, 64);
        csq  += __shfl_down(csq, off, 64);
        s2   += __shfl_down(s2, off, 64);
    }
    const int lane = t & 63, wv = t >> 6;
    if (lane == 0) {
        red[0][wv] = sx; red[1][wv] = sdot; red[2][wv] = scl;
        red[3][wv] = csq; red[4][wv] = s2;
    }
    __syncthreads();
    if (t == 0) {
        double Sx   = red[0][0] + red[0][1] + red[0][2] + red[0][3];
        double Sdot = red[1][0] + red[1][1] + red[1][2] + red[1][3];
        double Scl  = red[2][0] + red[2][1] + red[2][2] + red[2][3];
        double Sc   = red[3][0] + red[3][1] + red[3][2] + red[3][3];
        double S2   = red[4][0] + red[4][1] + red[4][2] + red[4][3];
        double sum_all  = (double)NC * Sx + (double)NB * Sc - 2.0 * S2;
        double sum_diag = Sx + Scl - 2.0 * Sdot;
        double center_loss = sum_diag / (double)NB;
        double sep_loss =
            (sum_all - sum_diag) / ((double)NB * (double)(NC - 1));
        out[0] = (float)(center_loss - 0.001 * sep_loss);
    }
}

extern "C" void kernel_launch(void* const* d_in, const int* in_sizes, int n_in,
                              void* d_out, int out_size, void* d_ws, size_t ws_size,
                              hipStream_t stream) {
    const float4* x4 = (const float4*)d_in[0];   // [8192, 2048] f32
    const float4* c4 = (const float4*)d_in[1];   // [1000, 2048] f32
    const int* labels = (const int*)d_in[2];     // [8192] i32

    float4* xp = (float4*)((char*)d_ws + XP_OFF);
    float4* cp = (float4*)((char*)d_ws + CP_OFF);
    float4* partials = (float4*)((char*)d_ws + PART_OFF);
    float* s2p = (float*)((char*)d_ws + S2_OFF);
    float* out = (float*)d_out;

    main_kernel<<<NBLOCKS, THREADS, 0, stream>>>(x4, c4, labels, xp, cp,
                                                 partials);
    reduce_kernel<<<RBLOCKS, THREADS, 0, stream>>>((const float*)xp,
                                                   (const float*)cp, s2p);
    finalize_kernel<<<1, THREADS, 0, stream>>>(partials, s2p, out);
}

// Round 5
// 117.192 us; speedup vs baseline: 2.6159x; 1.3183x over previous
//
#include <hip/hip_runtime.h>

// CenterLoss, closed form (clamp provably inactive for these inputs:
// pairwise sq-dists are 4096 +- ~130, far inside [1e-12,1e12]; absmax=0
// verified rounds 1-4):
//   Sum_all  = C*Sx + B*Sc - 2*S2,  S2 = sum_b (x_b . sc), sc = colsum(centers)
//   Sum_diag = Sx + Scl - 2*Sdot
//   loss = Sum_diag/B - 0.001*(Sum_all - Sum_diag)/(B*(C-1))
//
// Round-4 post-mortem: materializing per-block column sums of x (8 MB) and
// folding them (reduce_kernel) cost 48 us at 109 GB/s (VGPR=8, latency-bound
// strided walk). Inverted: compute sc FIRST (centers colsum, 8 MB, wide 2D
// kernel), then the x-pass folds s2 += x.sc into its dot loop. No big
// intermediate, no reduce kernel. Zero atomics (round-3 lesson). No memset
// needed: every consumed ws byte is written each call.

#define DD 2048
#define NB 8192
#define NC 1000
#define D4 (DD / 4)          // 512 float4 per row
#define THREADS 256
#define XROWS 8
#define XBLOCKS (NB / XROWS) // 1024
#define CTILES 8             // column tiles of 256 cols (64 float4)
#define CRG 8                // row groups of 125 rows (8*125 = 1000 exactly)
#define CBLOCKS (CTILES * CRG)

// ws layout (bytes):
//   cq  [CRG][2048] f32  @ 0      (64 KB)  centers colsum partial rows
//   csq [CBLOCKS]   f32  @ 65536  (256 B)  per-block Sc partials
//   part[XBLOCKS] float4 @ 65792  (16 KB)  per-x-block {sx, sdot, scl, s2}
#define CQ_OFF   0
#define CSQ_OFF  65536
#define PART_OFF 65792

__device__ __forceinline__ float dot4(float4 a, float4 b) {
    return a.x * b.x + a.y * b.y + a.z * b.z + a.w * b.w;
}
__device__ __forceinline__ void acc4(float4& a, float4 b) {
    a.x += b.x; a.y += b.y; a.z += b.z; a.w += b.w;
}

// Kernel 1: centers -> cq (8 partial colsum rows) + csq partials.
// 64 blocks = 8 col-tiles x 8 row-groups. Wave lanes span 64 consecutive
// float4 (1 KB coalesced); each thread ~31 independent loads.
__global__ __launch_bounds__(THREADS) void centers_kernel(
        const float4* __restrict__ c4, float4* __restrict__ cq,
        float* __restrict__ csq_part) {
    const int t = threadIdx.x;
    const int tile = blockIdx.x & (CTILES - 1);
    const int rg = blockIdx.x >> 3;
    const int col4 = tile * 64 + (t & 63);
    const int rlane = t >> 6;                 // 0..3
    const int row0 = rg * 125;

    float4 acc = make_float4(0.f, 0.f, 0.f, 0.f);
    float csq = 0.f;
    for (int r = rlane; r < 125; r += 4) {
        float4 v = c4[(size_t)(row0 + r) * D4 + col4];
        acc4(acc, v);
        csq += dot4(v, v);
    }

    __shared__ float4 lds[4][64];
    lds[rlane][t & 63] = acc;
    __syncthreads();
    if (t < 64) {
        float4 s = lds[0][t];
        acc4(s, lds[1][t]); acc4(s, lds[2][t]); acc4(s, lds[3][t]);
        cq[rg * 512 + tile * 64 + t] = s;
    }

    // block-reduce csq
    __shared__ float red[THREADS / 64];
    for (int off = 32; off > 0; off >>= 1) csq += __shfl_down(csq, off, 64);
    const int lane = t & 63, wv = t >> 6;
    if (lane == 0) red[wv] = csq;
    __syncthreads();
    if (t == 0)
        csq_part[blockIdx.x] = red[0] + red[1] + red[2] + red[3];
}

// Kernel 2: x -> {sx, sdot, scl, s2} per block. Folds cq's 8 partial rows
// into sc registers at startup (broadcast, L2/L3-hot). Depth-1 software
// pipeline on the 4 streaming loads per row (round-3 shape that worked).
__global__ __launch_bounds__(THREADS) void x_kernel(
        const float4* __restrict__ x4, const float4* __restrict__ c4,
        const int* __restrict__ labels, const float4* __restrict__ cq,
        float4* __restrict__ partials) {
    const int t = threadIdx.x;
    const int b = blockIdx.x;

    // fold sc for this thread's two column groups
    float4 sc0 = make_float4(0.f, 0.f, 0.f, 0.f);
    float4 sc1 = make_float4(0.f, 0.f, 0.f, 0.f);
#pragma unroll
    for (int r = 0; r < CRG; ++r) {
        acc4(sc0, cq[r * 512 + t]);
        acc4(sc1, cq[r * 512 + 256 + t]);
    }

    const int rows0 = b * XROWS;
    int labs[XROWS];
#pragma unroll
    for (int r = 0; r < XROWS; ++r) labs[r] = labels[rows0 + r];  // uniform

    const float4* xr = x4 + (size_t)rows0 * D4 + t;
    float sx = 0.f, sdot = 0.f, scl = 0.f, s2 = 0.f;

    float4 xa = xr[0], xb = xr[256];
    const float4* cr = c4 + (size_t)labs[0] * D4 + t;
    float4 ca = cr[0], cb = cr[256];
#pragma unroll
    for (int r = 0; r < XROWS; ++r) {
        float4 nxa, nxb, nca, ncb;
        if (r + 1 < XROWS) {
            nxa = xr[(r + 1) * D4];
            nxb = xr[(r + 1) * D4 + 256];
            const float4* np = c4 + (size_t)labs[r + 1] * D4 + t;
            nca = np[0];
            ncb = np[256];
        }
        sx   += dot4(xa, xa) + dot4(xb, xb);
        sdot += dot4(xa, ca) + dot4(xb, cb);
        scl  += dot4(ca, ca) + dot4(cb, cb);
        s2   += dot4(xa, sc0) + dot4(xb, sc1);
        if (r + 1 < XROWS) { xa = nxa; xb = nxb; ca = nca; cb = ncb; }
    }

    __shared__ float red[4][THREADS / 64];
    for (int off = 32; off > 0; off >>= 1) {
        sx   += __shfl_down(sx, off, 64);
        sdot += __shfl_down(sdot, off, 64);
        scl  += __shfl_down(scl, off, 64);
        s2   += __shfl_down(s2, off, 64);
    }
    const int lane = t & 63, wv = t >> 6;
    if (lane == 0) {
        red[0][wv] = sx; red[1][wv] = sdot;
        red[2][wv] = scl; red[3][wv] = s2;
    }
    __syncthreads();
    if (t == 0) {
        float4 s;
        s.x = red[0][0] + red[0][1] + red[0][2] + red[0][3];
        s.y = red[1][0] + red[1][1] + red[1][2] + red[1][3];
        s.z = red[2][0] + red[2][1] + red[2][2] + red[2][3];
        s.w = red[3][0] + red[3][1] + red[3][2] + red[3][3];
        partials[b] = s;
    }
}

__global__ __launch_bounds__(THREADS) void finalize_kernel(
        const float4* __restrict__ partials, const float* __restrict__ csq_part,
        float* __restrict__ out) {
    const int t = threadIdx.x;

    double sx = 0.0, sdot = 0.0, scl = 0.0, s2 = 0.0, csq = 0.0;
    for (int i = t; i < XBLOCKS; i += THREADS) {
        float4 p = partials[i];
        sx += (double)p.x; sdot += (double)p.y;
        scl += (double)p.z; s2 += (double)p.w;
    }
    if (t < CBLOCKS) csq = (double)csq_part[t];

    __shared__ double red[5][THREADS / 64];
    for (int off = 32; off > 0; off >>= 1) {
        sx   += __shfl_down(sx, off, 64);
        sdot += __shfl_down(sdot, off, 64);
        scl  += __shfl_down(scl, off, 64);
        s2   += __shfl_down(s2, off, 64);
        csq  += __shfl_down(csq, off, 64);
    }
    const int lane = t & 63, wv = t >> 6;
    if (lane == 0) {
        red[0][wv] = sx; red[1][wv] = sdot; red[2][wv] = scl;
        red[3][wv] = s2; red[4][wv] = csq;
    }
    __syncthreads();
    if (t == 0) {
        double Sx   = red[0][0] + red[0][1] + red[0][2] + red[0][3];
        double Sdot = red[1][0] + red[1][1] + red[1][2] + red[1][3];
        double Scl  = red[2][0] + red[2][1] + red[2][2] + red[2][3];
        double S2   = red[3][0] + red[3][1] + red[3][2] + red[3][3];
        double Sc   = red[4][0] + red[4][1] + red[4][2] + red[4][3];
        double sum_all  = (double)NC * Sx + (double)NB * Sc - 2.0 * S2;
        double sum_diag = Sx + Scl - 2.0 * Sdot;
        double center_loss = sum_diag / (double)NB;
        double sep_loss =
            (sum_all - sum_diag) / ((double)NB * (double)(NC - 1));
        out[0] = (float)(center_loss - 0.001 * sep_loss);
    }
}

extern "C" void kernel_launch(void* const* d_in, const int* in_sizes, int n_in,
                              void* d_out, int out_size, void* d_ws, size_t ws_size,
                              hipStream_t stream) {
    const float4* x4 = (const float4*)d_in[0];   // [8192, 2048] f32
    const float4* c4 = (const float4*)d_in[1];   // [1000, 2048] f32
    const int* labels = (const int*)d_in[2];     // [8192] i32

    float4* cq = (float4*)((char*)d_ws + CQ_OFF);
    float* csq_part = (float*)((char*)d_ws + CSQ_OFF);
    float4* partials = (float4*)((char*)d_ws + PART_OFF);
    float* out = (float*)d_out;

    centers_kernel<<<CBLOCKS, THREADS, 0, stream>>>(c4, cq, csq_part);
    x_kernel<<<XBLOCKS, THREADS, 0, stream>>>(x4, c4, labels,
                                              (const float4*)cq, partials);
    finalize_kernel<<<1, THREADS, 0, stream>>>(partials, csq_part, out);
}

// Round 6
// 110.954 us; speedup vs baseline: 2.7630x; 1.0562x over previous
//
#include <hip/hip_runtime.h>

// CenterLoss, closed form (clamp provably inactive for these inputs:
// pairwise sq-dists are 4096 +- ~130, far inside [1e-12,1e12]; absmax=0
// verified rounds 1-5):
//   Sum_all  = C*Sx + B*Sc - 2*S2,  S2 = sum_b (x_b . sc), sc = colsum(centers)
//   Sum_diag = Sx + Scl - 2*Sdot
//   loss = Sum_diag/B - 0.001*(Sum_all - Sum_diag)/(B*(C-1))
//
// Round-5 post-mortem: top dispatches are the HARNESS's 268 MB ws-poison
// fills (42 us) + input restores (~23 us) — fixed cost inside dur_us. Our
// controllable part is x_kernel (~40 us, grid-limited at 45% occupancy in
// round 1's counters). This round: 2048 half-width x-blocks (VGPR<=64 =>
// 8 waves/SIMD), depth-2 pipeline (4 loads in flight/thread), and a tiny
// sc_fold so x reads final sc directly. Zero atomics (round-3 lesson),
// no big intermediates (round-4 lesson), no memset.

#define DD 2048
#define NB 8192
#define NC 1000
#define D4 (DD / 4)            // 512 float4 per row
#define HALF4 256              // float4 per half-row
#define THREADS 256
#define XROWS 8
#define XBLOCKS ((NB / XROWS) * 2)   // 2048: row-group x column-half
#define CTILES 8
#define CRG 8
#define CBLOCKS (CTILES * CRG)       // 64

// ws layout (bytes):
//   cq  [CRG][2048] f32  @ 0      (64 KB)  centers colsum partial rows
//   sc  [2048]      f32  @ 65536  (8 KB)   final centers colsum
//   csq [CBLOCKS]   f32  @ 73728  (256 B)  per-block Sc partials
//   part[XBLOCKS] float4 @ 73984  (32 KB)  per-x-block {sx, sdot, scl, s2}
#define CQ_OFF   0
#define SC_OFF   65536
#define CSQ_OFF  73728
#define PART_OFF 73984

__device__ __forceinline__ float dot4(float4 a, float4 b) {
    return a.x * b.x + a.y * b.y + a.z * b.z + a.w * b.w;
}
__device__ __forceinline__ void acc4(float4& a, float4 b) {
    a.x += b.x; a.y += b.y; a.z += b.z; a.w += b.w;
}

// Kernel 1: centers -> cq (8 partial colsum rows) + csq partials.
// 64 blocks = 8 col-tiles x 8 row-groups of 125 rows.
__global__ __launch_bounds__(THREADS) void centers_kernel(
        const float4* __restrict__ c4, float4* __restrict__ cq,
        float* __restrict__ csq_part) {
    const int t = threadIdx.x;
    const int tile = blockIdx.x & (CTILES - 1);
    const int rg = blockIdx.x >> 3;
    const int col4 = tile * 64 + (t & 63);
    const int rlane = t >> 6;                 // 0..3
    const int row0 = rg * 125;

    float4 acc = make_float4(0.f, 0.f, 0.f, 0.f);
    float csq = 0.f;
#pragma unroll 4
    for (int r = rlane; r < 125; r += 4) {
        float4 v = c4[(size_t)(row0 + r) * D4 + col4];
        acc4(acc, v);
        csq += dot4(v, v);
    }

    __shared__ float4 lds[4][64];
    lds[rlane][t & 63] = acc;
    __syncthreads();
    if (t < 64) {
        float4 s = lds[0][t];
        acc4(s, lds[1][t]); acc4(s, lds[2][t]); acc4(s, lds[3][t]);
        cq[rg * 512 + tile * 64 + t] = s;
    }

    __shared__ float red[THREADS / 64];
    for (int off = 32; off > 0; off >>= 1) csq += __shfl_down(csq, off, 64);
    const int lane = t & 63, wv = t >> 6;
    if (lane == 0) red[wv] = csq;
    __syncthreads();
    if (t == 0)
        csq_part[blockIdx.x] = red[0] + red[1] + red[2] + red[3];
}

// Kernel 2: fold cq[8][2048] -> sc[2048]. 2 blocks x 256 threads,
// one float4 column each, 8 independent L2-hot loads.
__global__ __launch_bounds__(THREADS) void sc_fold_kernel(
        const float4* __restrict__ cq, float4* __restrict__ sc4) {
    const int idx = blockIdx.x * THREADS + threadIdx.x;   // 0..511
    float4 s = cq[idx];
#pragma unroll
    for (int r = 1; r < CRG; ++r) acc4(s, cq[r * 512 + idx]);
    sc4[idx] = s;
}

// Kernel 3: x -> {sx, sdot, scl, s2} per block. 2048 blocks: row-group
// (8 rows) x column-half (1024 cols). One float4 per thread per row,
// depth-2 software pipeline, fully unrolled.
__global__ __launch_bounds__(THREADS) void x_kernel(
        const float4* __restrict__ x4, const float4* __restrict__ c4,
        const int* __restrict__ labels, const float4* __restrict__ sc4,
        float4* __restrict__ partials) {
    const int t = threadIdx.x;
    const int b = blockIdx.x;
    const int rowgrp = b >> 1;
    const int h = (b & 1) * HALF4;          // float4 offset of this half
    const int rows0 = rowgrp * XROWS;

    const float4 sc = sc4[h + t];

    int labs[XROWS];
#pragma unroll
    for (int r = 0; r < XROWS; ++r) labs[r] = labels[rows0 + r];  // uniform

    const float4* xr = x4 + (size_t)rows0 * D4 + h + t;
    const float4* cbase = c4 + h + t;

    float sx = 0.f, sdot = 0.f, scl = 0.f, s2 = 0.f;

    // depth-2 pipeline: rows r and r+1 in flight while consuming row r
    float4 xa = xr[0],      ca = cbase[(size_t)labs[0] * D4];
    float4 xb = xr[D4],     cb = cbase[(size_t)labs[1] * D4];
#pragma unroll
    for (int r = 0; r < XROWS; ++r) {
        float4 nx, nc;
        if (r + 2 < XROWS) {
            nx = xr[(size_t)(r + 2) * D4];
            nc = cbase[(size_t)labs[r + 2] * D4];
        }
        sx   += dot4(xa, xa);
        sdot += dot4(xa, ca);
        scl  += dot4(ca, ca);
        s2   += dot4(xa, sc);
        xa = xb; ca = cb;
        if (r + 2 < XROWS) { xb = nx; cb = nc; }
    }

    __shared__ float red[4][THREADS / 64];
    for (int off = 32; off > 0; off >>= 1) {
        sx   += __shfl_down(sx, off, 64);
        sdot += __shfl_down(sdot, off, 64);
        scl  += __shfl_down(scl, off, 64);
        s2   += __shfl_down(s2, off, 64);
    }
    const int lane = t & 63, wv = t >> 6;
    if (lane == 0) {
        red[0][wv] = sx; red[1][wv] = sdot;
        red[2][wv] = scl; red[3][wv] = s2;
    }
    __syncthreads();
    if (t == 0) {
        float4 s;
        s.x = red[0][0] + red[0][1] + red[0][2] + red[0][3];
        s.y = red[1][0] + red[1][1] + red[1][2] + red[1][3];
        s.z = red[2][0] + red[2][1] + red[2][2] + red[2][3];
        s.w = red[3][0] + red[3][1] + red[3][2] + red[3][3];
        partials[b] = s;
    }
}

__global__ __launch_bounds__(THREADS) void finalize_kernel(
        const float4* __restrict__ partials, const float* __restrict__ csq_part,
        float* __restrict__ out) {
    const int t = threadIdx.x;

    double sx = 0.0, sdot = 0.0, scl = 0.0, s2 = 0.0, csq = 0.0;
    for (int i = t; i < XBLOCKS; i += THREADS) {
        float4 p = partials[i];
        sx += (double)p.x; sdot += (double)p.y;
        scl += (double)p.z; s2 += (double)p.w;
    }
    if (t < CBLOCKS) csq = (double)csq_part[t];

    __shared__ double red[5][THREADS / 64];
    for (int off = 32; off > 0; off >>= 1) {
        sx   += __shfl_down(sx, off, 64);
        sdot += __shfl_down(sdot, off, 64);
        scl  += __shfl_down(scl, off, 64);
        s2   += __shfl_down(s2, off, 64);
        csq  += __shfl_down(csq, off, 64);
    }
    const int lane = t & 63, wv = t >> 6;
    if (lane == 0) {
        red[0][wv] = sx; red[1][wv] = sdot; red[2][wv] = scl;
        red[3][wv] = s2; red[4][wv] = csq;
    }
    __syncthreads();
    if (t == 0) {
        double Sx   = red[0][0] + red[0][1] + red[0][2] + red[0][3];
        double Sdot = red[1][0] + red[1][1] + red[1][2] + red[1][3];
        double Scl  = red[2][0] + red[2][1] + red[2][2] + red[2][3];
        double S2   = red[3][0] + red[3][1] + red[3][2] + red[3][3];
        double Sc   = red[4][0] + red[4][1] + red[4][2] + red[4][3];
        double sum_all  = (double)NC * Sx + (double)NB * Sc - 2.0 * S2;
        double sum_diag = Sx + Scl - 2.0 * Sdot;
        double center_loss = sum_diag / (double)NB;
        double sep_loss =
            (sum_all - sum_diag) / ((double)NB * (double)(NC - 1));
        out[0] = (float)(center_loss - 0.001 * sep_loss);
    }
}

extern "C" void kernel_launch(void* const* d_in, const int* in_sizes, int n_in,
                              void* d_out, int out_size, void* d_ws, size_t ws_size,
                              hipStream_t stream) {
    const float4* x4 = (const float4*)d_in[0];   // [8192, 2048] f32
    const float4* c4 = (const float4*)d_in[1];   // [1000, 2048] f32
    const int* labels = (const int*)d_in[2];     // [8192] i32

    float4* cq = (float4*)((char*)d_ws + CQ_OFF);
    float4* sc = (float4*)((char*)d_ws + SC_OFF);
    float* csq_part = (float*)((char*)d_ws + CSQ_OFF);
    float4* partials = (float4*)((char*)d_ws + PART_OFF);
    float* out = (float*)d_out;

    centers_kernel<<<CBLOCKS, THREADS, 0, stream>>>(c4, cq, csq_part);
    sc_fold_kernel<<<2, THREADS, 0, stream>>>((const float4*)cq, sc);
    x_kernel<<<XBLOCKS, THREADS, 0, stream>>>(x4, c4, labels,
                                              (const float4*)sc, partials);
    finalize_kernel<<<1, THREADS, 0, stream>>>(partials, csq_part, out);
}